// Round 12
// baseline (93.029 us; speedup 1.0000x reference)
//
#include <hip/hip_runtime.h>
#include <hip/hip_fp16.h>

#define VOL    256
#define NPROJ  256
#define NDET   384
#define NS     256
#define BW     65                  // band width (texture px); 4 bands cover [0,260)
#define XST    71                  // x-band stride (cols/row incl pad; odd -> all banks)
#define XROWS  257                 // V-rows uy = 0..256
#define XBSZ   (XROWS * XST)       // 18247 dwords
#define XBSZP  18248               // padded to uint4
#define XB4    (XBSZP / 4)         // 4562
#define YST    261                 // y-band stride (odd)
#define YROWS  69                  // 65 rows + margins
#define YBSZ   (YROWS * YST)       // 18009 dwords
#define YBSZP  18012
#define YB4    (YBSZP / 4)         // 4503
#define TPB    768                 // 12 waves; 256 blocks = 1/CU; 2 angles/block

typedef _Float16 hvec2 __attribute__((ext_vector_type(2)));

// vertical-pair value: VP(uy,ux) = half2{ P(uy,ux), P(uy+1,ux) },
// P(py,px) = img[py-1][px-1], zero outside.
__device__ __forceinline__ uint vp_pack(const float* im, int uy, int ux) {
    int x = ux - 1;
    if ((unsigned)x >= 256u) return 0u;
    float v0 = ((unsigned)(uy - 1) < 256u) ? im[((uy - 1) << 8) + x] : 0.0f;
    float v1 = ((unsigned)uy       < 256u) ? im[(uy << 8) + x]       : 0.0f;
    __half2 h2 = __floats2half2_rn(v0, v1);
    return *reinterpret_cast<uint*>(&h2);
}

// x-band textures: Gx[(bt*4+b)*XBSZP + r*XST + c] = VP(r, 65b-2+c)
__global__ void xband_build(const float* __restrict__ src, uint* __restrict__ dst) {
    int idx = blockIdx.x * blockDim.x + threadIdx.x;
    if (idx >= 2 * 4 * XBSZP) return;
    int g  = idx / XBSZP;
    int dd = idx - g * XBSZP;
    uint val = 0u;
    if (dd < XBSZ) {
        int r  = dd / XST;
        int c  = dd - r * XST;
        int ux = BW * (g & 3) - 2 + c;
        val = vp_pack(src + ((g >> 2) << 16), r, ux);
    }
    dst[idx] = val;
}

// y-band textures: Gy[(bt*4+b)*YBSZP + r*YST + c] = VP(65b-2+r, c)
__global__ void yband_build(const float* __restrict__ src, uint* __restrict__ dst) {
    int idx = blockIdx.x * blockDim.x + threadIdx.x;
    if (idx >= 2 * 4 * YBSZP) return;
    int g  = idx / YBSZP;
    int dd = idx - g * YBSZP;
    uint val = 0u;
    if (dd < YBSZ) {
        int r  = dd / YST;
        int c  = dd - r * YST;
        int uy = BW * (g & 3) - 2 + r;
        val = vp_pack(src + ((g >> 2) << 16), uy, c);
    }
    dst[idx] = val;
}

// One block per 768-ray group (2 adjacent angles). Marches 4 texture bands
// sequentially (stage->sync->process); bands cut along the block's dominant
// ray direction so per-pass work is uniform. 1 ds_read2_b32 per sample.
__global__ __launch_bounds__(TPB) void fanproj_kernel(const uint4* __restrict__ Gx,
                                                      const uint4* __restrict__ Gy,
                                                      float* __restrict__ out) {
    __shared__ uint4 s4[XB4];                          // 72,992 B
    const uint* sV = reinterpret_cast<const uint*>(s4);

    int tid = threadIdx.x;
    int grp = blockIdx.x;
    int ray = grp * TPB + tid;                         // b*P*D + p*D + d
    int bt  = grp >> 7;                                // 128 groups per batch

    int d  = ray % NDET;
    int pb = ray / NDET;
    int p  = pb & (NPROJ - 1);

    const float dt = 1.4142135623730951f;              // diag / NS = sqrt(2)
    const float t0 = 219.68777079743137f;              // SID - diag/2 + 0.5*dt
    const float DTH = 6.283185307179586f / (float)NPROJ;

    float theta = (float)p * DTH;
    float st, ct;
    __sincosf(theta, &st, &ct);

    // block-uniform band-direction class from the block's midpoint angle
    float thm = ((float)((grp << 1) & 255) + 0.5f) * DTH;
    float cm, sm;
    __sincosf(thm, &sm, &cm);                          // sm=sin, cm=cos
    bool useX = fabsf(cm) >= fabsf(sm);

    float srcx = -400.0f * ct;
    float srcy = -400.0f * st;
    float off  = ((float)d - 191.5f) * 1.2f;
    float rx   = fmaf(800.0f, ct, -off * st);
    float ry   = fmaf(800.0f, st,  off * ct);
    float n2   = rx * rx + ry * ry;
    float rn   = rsqrtf(n2);
    rn = rn * (1.5f - 0.5f * n2 * rn * rn);            // one Newton step
    rx *= rn;
    ry *= rn;

    // texture coords: X(s)=bxu+s*sx, Y(s)=byu+s*sy, valid in [0,257)
    float bxu = fmaf(t0, rx, srcx) + 128.5f;
    float byu = fmaf(t0, ry, srcy) + 128.5f;
    float sx  = dt * rx;
    float sy  = dt * ry;

    // global guard-free interval (EPS-shrunk; verified R8-R11)
    const float EPS = 2e-3f;
    float sxs = (fabsf(sx) < 1e-9f) ? copysignf(1e-9f, sx) : sx;
    float sys = (fabsf(sy) < 1e-9f) ? copysignf(1e-9f, sy) : sy;
    float isx = 1.0f / sxs;
    float isy = 1.0f / sys;
    float ax0 = (0.0f - bxu) * isx, ax1 = (257.0f - bxu) * isx;
    float ay0 = (0.0f - byu) * isy, ay1 = (257.0f - byu) * isy;
    float lo  = fmaxf(fminf(ax0, ax1), fminf(ay0, ay1)) + EPS;
    float hi  = fminf(fmaxf(ax0, ax1), fmaxf(ay0, ay1)) - EPS;
    lo = fminf(fmaxf(lo, -1.0f), 300.0f);
    hi = fminf(fmaxf(hi, -1.0f), 300.0f);
    int slo = max(0,      (int)ceilf(lo));
    int shi = min(NS - 1, (int)floorf(hi));

    // per-lane band intervals: partition [slo,shi] at major-coord = 65/130/195
    float mB  = useX ? bxu : byu;
    float mIS = useX ? isx : isy;
    bool  pos = (useX ? sxs : sys) > 0.0f;
    float t1 = fminf(fmaxf(( 65.0f - mB) * mIS, -2.0f), 300.0f);
    float t2 = fminf(fmaxf((130.0f - mB) * mIS, -2.0f), 300.0f);
    float t3 = fminf(fmaxf((195.0f - mB) * mIS, -2.0f), 300.0f);
    int pLo0, pHi0, pLo1, pHi1, pLo2, pHi2, pLo3, pHi3;
    if (pos) {                                         // bands visited 0,1,2,3
        int k1 = min(max((int)ceilf(t1), slo), shi + 1);
        int k2 = min(max((int)ceilf(t2), k1),  shi + 1);
        int k3 = min(max((int)ceilf(t3), k2),  shi + 1);
        pLo0 = slo; pHi0 = k1 - 1;
        pLo1 = k1;  pHi1 = k2 - 1;
        pLo2 = k2;  pHi2 = k3 - 1;
        pLo3 = k3;  pHi3 = shi;
    } else {                                           // bands visited 3,2,1,0
        int j1 = min(max((int)floorf(t1) + 1, slo), shi + 1);
        int j2 = min(max((int)floorf(t2) + 1, slo), j1);
        int j3 = min(max((int)floorf(t3) + 1, slo), j2);
        pLo0 = j1;  pHi0 = shi;
        pLo1 = j2;  pHi1 = j1 - 1;
        pLo2 = j3;  pHi2 = j2 - 1;
        pLo3 = slo; pHi3 = j3 - 1;
    }

#define PASS(BND, PLO, PHI) do {                                              \
        __syncthreads();                                                      \
        {                                                                     \
            const uint4* gb = useX                                            \
                ? Gx + (size_t)((bt << 2) + (BND)) * XB4                      \
                : Gy + (size_t)((bt << 2) + (BND)) * YB4;                     \
            int n4 = useX ? XB4 : YB4;                                        \
            for (int i = tid; i < n4; i += TPB) s4[i] = gb[i];                \
        }                                                                     \
        __syncthreads();                                                      \
        int A = useX ? XST : YST;                                             \
        int C = useX ? -(BW * (BND) - 2) : -(BW * (BND) - 2) * YST;           \
        float sf = (float)(PLO);                                              \
        for (int s = (PLO); s <= (PHI); ++s) {                                \
            float X = fmaf(sf, sx, bxu);                                      \
            float Y = fmaf(sf, sy, byu);                                      \
            sf += 1.0f;                                                       \
            float Xf = floorf(X);                                             \
            float Yf = floorf(Y);                                             \
            float wx = X - Xf;                                                \
            float wy = Y - Yf;                                                \
            int ux = (int)Xf;                                                 \
            int uy = (int)Yf;                                                 \
            int addr = uy * A + ux + C;                                       \
            uint V0 = sV[addr];                                               \
            uint V1 = sV[addr + 1];                                           \
            hvec2 hw = __builtin_bit_cast(hvec2,                              \
                           __builtin_amdgcn_cvt_pkrtz(1.0f - wy, wy));        \
            hvec2 a0 = __builtin_bit_cast(hvec2, V0);                         \
            hvec2 a1 = __builtin_bit_cast(hvec2, V1);                         \
            float c0 = __builtin_amdgcn_fdot2(a0, hw, 0.0f, false);           \
            float c1 = __builtin_amdgcn_fdot2(a1, hw, 0.0f, false);           \
            acc = fmaf(wx, c1 - c0, acc + c0);                                \
        }                                                                     \
    } while (0)

    float acc = 0.0f;
    PASS(0, pLo0, pHi0);
    PASS(1, pLo1, pHi1);
    PASS(2, pLo2, pHi2);
    PASS(3, pLo3, pHi3);
#undef PASS

    out[ray] = acc * dt;                               // every ray exactly once
}

extern "C" void kernel_launch(void* const* d_in, const int* in_sizes, int n_in,
                              void* d_out, int out_size, void* d_ws, size_t ws_size,
                              hipStream_t stream) {
    const float* x = (const float*)d_in[0];
    float* out     = (float*)d_out;
    uint* gx       = (uint*)d_ws;                      // 2*4*XBSZP dw = 584 KB
    uint* gy       = gx + 2 * 4 * XBSZP;               // 2*4*YBSZP dw = 576 KB

    int nx = 2 * 4 * XBSZP;                            // 145984
    xband_build<<<(nx + 255) / 256, 256, 0, stream>>>(x, gx);
    int ny = 2 * 4 * YBSZP;                            // 144096
    yband_build<<<(ny + 255) / 256, 256, 0, stream>>>(x, gy);

    // 256 blocks x 768 threads = 196608 rays; 1 block/CU; no atomics
    fanproj_kernel<<<256, TPB, 0, stream>>>((const uint4*)gx, (const uint4*)gy, out);
}

// Round 13
// 90.823 us; speedup vs baseline: 1.0243x; 1.0243x over previous
//
#include <hip/hip_runtime.h>
#include <hip/hip_fp16.h>

#define NPROJ  256
#define NDET   384
#define NS     256
#define TW     258                 // texture entries per row (uy,ux in [0,258))
#define TN     (TW * TW)           // 66564 entries per batch image
#define TPB    256

typedef _Float16 hvec2 __attribute__((ext_vector_type(2)));

// vertical-pair value: VP(uy,ux) = half2{ P(uy,ux), P(uy+1,ux) },
// P(py,px) = img[py-1][px-1], zero outside (verified R10/R12 builder).
__device__ __forceinline__ uint vp_pack(const float* im, int uy, int ux) {
    int x = ux - 1;
    if ((unsigned)x >= 256u) return 0u;
    float v0 = ((unsigned)(uy - 1) < 256u) ? im[((uy - 1) << 8) + x] : 0.0f;
    float v1 = ((unsigned)uy       < 256u) ? im[(uy << 8) + x]       : 0.0f;
    __half2 h2 = __floats2half2_rn(v0, v1);
    return *reinterpret_cast<uint*>(&h2);
}

// Gq[b*TN + uy*TW + ux] = { VP(uy,ux), VP(uy,ux+1) } : one 8B load fetches
// the whole bilinear footprint for floor coords (uy,ux).
__global__ void quad_build(const float* __restrict__ src, uint2* __restrict__ dst) {
    int idx = blockIdx.x * blockDim.x + threadIdx.x;   // over 2*TN
    if (idx >= 2 * TN) return;
    int b  = idx / TN;
    int e  = idx - b * TN;
    int uy = e / TW;
    int ux = e - uy * TW;
    const float* im = src + (b << 16);
    uint2 q;
    q.x = vp_pack(im, uy, ux);
    q.y = vp_pack(im, uy, ux + 1);
    dst[idx] = q;
}

// One thread = one ray x one s-half. Chunks of 4 samples: 4 addr -> 4 loads
// in flight -> 4 consumes. Tail samples weight-zeroed, address med3-clamped.
__global__ __launch_bounds__(TPB, 4) void fanproj_kernel(const uint2* __restrict__ Gq,
                                                         float* __restrict__ out) {
    int tid = threadIdx.x;
    int c   = blockIdx.x & 1;                          // s-half selector
    int grp = blockIdx.x >> 1;
    int ray = grp * TPB + tid;                         // b*P*D + p*D + d
    int b   = grp >= 384;                              // batch (384 grps each)

    int d  = ray % NDET;
    int pb = ray / NDET;
    int p  = pb & (NPROJ - 1);

    const float dt = 1.4142135623730951f;              // diag / NS = sqrt(2)
    const float t0 = 219.68777079743137f;              // SID - diag/2 + 0.5*dt

    float theta = (float)p * (6.283185307179586f / (float)NPROJ);
    float st, ct;
    __sincosf(theta, &st, &ct);

    float srcx = -400.0f * ct;
    float srcy = -400.0f * st;
    float off  = ((float)d - 191.5f) * 1.2f;
    float rx   = fmaf(800.0f, ct, -off * st);
    float ry   = fmaf(800.0f, st,  off * ct);
    float n2   = rx * rx + ry * ry;
    float rn   = rsqrtf(n2);
    rn = rn * (1.5f - 0.5f * n2 * rn * rn);            // one Newton step
    rx *= rn;
    ry *= rn;

    // texture coords: X(s)=bxu+s*sx, Y(s)=byu+s*sy, footprint valid in [0,257)
    float bxu = fmaf(t0, rx, srcx) + 128.5f;
    float byu = fmaf(t0, ry, srcy) + 128.5f;
    float sx  = dt * rx;
    float sy  = dt * ry;

    // guard-free interval, EPS-shrunk (verified R8-R12); med3 clamp below
    // additionally protects against float-march drift at the endpoints.
    const float EPS = 2e-3f;
    float sxs = (fabsf(sx) < 1e-9f) ? copysignf(1e-9f, sx) : sx;
    float sys = (fabsf(sy) < 1e-9f) ? copysignf(1e-9f, sy) : sy;
    float isx = 1.0f / sxs;
    float isy = 1.0f / sys;
    float ax0 = (0.0f - bxu) * isx, ax1 = (257.0f - bxu) * isx;
    float ay0 = (0.0f - byu) * isy, ay1 = (257.0f - byu) * isy;
    float lof = fmaxf(fminf(ax0, ax1), fminf(ay0, ay1)) + EPS;
    float hif = fminf(fmaxf(ax0, ax1), fmaxf(ay0, ay1)) - EPS;
    lof = fminf(fmaxf(lof, -1.0f), 300.0f);
    hif = fminf(fmaxf(hif, -1.0f), 300.0f);
    int slo = max(0,      (int)ceilf(lof));
    int shi = min(NS - 1, (int)floorf(hif));

    int mid = (slo + shi + 1) >> 1;                    // split interval in 2
    int lo  = c ? mid : slo;
    int hi  = c ? shi : (mid - 1);
    int rem = hi - lo;                                 // samples-1 remaining

    const uint2* Gb = Gq + (size_t)(b ? TN : 0);

    float sx2 = sx + sx, sy2 = sy + sy;
    float X = fmaf((float)lo, sx, bxu);
    float Y = fmaf((float)lo, sy, byu);
    float acc0 = 0.0f, acc1 = 0.0f;

#define ADDR(K, XX, YY)                                                       \
    float xf##K = floorf(XX), yf##K = floorf(YY);                             \
    float wx##K = (XX) - xf##K, wy##K = (YY) - yf##K;                         \
    float aF##K = fmaf(yf##K, 258.0f, xf##K);                                 \
    aF##K = fminf(fmaxf(aF##K, 0.0f), 66563.0f);                              \
    int ai##K = (int)aF##K;

#define CONSUME(K, Q, ACC) {                                                  \
    uint hwb = __builtin_bit_cast(uint,                                       \
        __builtin_amdgcn_cvt_pkrtz(1.0f - wy##K, wy##K));                     \
    hwb = (rem >= K) ? hwb : 0u;       /* tail mask: zero weight */           \
    hvec2 hw = __builtin_bit_cast(hvec2, hwb);                                \
    float c0 = __builtin_amdgcn_fdot2(                                        \
        __builtin_bit_cast(hvec2, (Q).x), hw, 0.0f, false);                   \
    float c1 = __builtin_amdgcn_fdot2(                                        \
        __builtin_bit_cast(hvec2, (Q).y), hw, 0.0f, false);                   \
    ACC = fmaf(wx##K, c1 - c0, ACC + c0);                                     \
}

    while (rem >= 0) {
        float X1 = X + sx,   Y1 = Y + sy;
        float X2 = X + sx2,  Y2 = Y + sy2;
        float X3 = X2 + sx,  Y3 = Y2 + sy;
        ADDR(0, X,  Y)
        ADDR(1, X1, Y1)
        ADDR(2, X2, Y2)
        ADDR(3, X3, Y3)
        uint2 q0 = Gb[ai0];                            // 4 loads in flight
        uint2 q1 = Gb[ai1];
        uint2 q2 = Gb[ai2];
        uint2 q3 = Gb[ai3];
        CONSUME(0, q0, acc0)
        CONSUME(1, q1, acc1)
        CONSUME(2, q2, acc0)
        CONSUME(3, q3, acc1)
        X = X2 + sx2;
        Y = Y2 + sy2;
        rem -= 4;
    }
#undef ADDR
#undef CONSUME

    if (hi >= lo) atomicAdd(&out[ray], (acc0 + acc1) * dt);
}

extern "C" void kernel_launch(void* const* d_in, const int* in_sizes, int n_in,
                              void* d_out, int out_size, void* d_ws, size_t ws_size,
                              hipStream_t stream) {
    const float* x = (const float*)d_in[0];
    float* out     = (float*)d_out;
    uint2* Gq      = (uint2*)d_ws;                     // 2*TN*8 B = 1.07 MB

    hipMemsetAsync(out, 0, (size_t)out_size * sizeof(float), stream);

    int nent = 2 * TN;                                 // 133128
    quad_build<<<(nent + 255) / 256, 256, 0, stream>>>(x, Gq);

    // 1536 blocks = 768 ray-groups x 2 s-halves
    fanproj_kernel<<<1536, TPB, 0, stream>>>(Gq, out);
}

// Round 14
// 81.850 us; speedup vs baseline: 1.1366x; 1.1096x over previous
//
#include <hip/hip_runtime.h>
#include <hip/hip_fp16.h>

#define NPROJ  256
#define NDET   384
#define NS     256
#define TW     258                 // texture entries per row (uy,ux in [0,258))
#define TN     (TW * TW)           // 66564 entries per batch image
#define TPB    256

typedef _Float16 hvec2 __attribute__((ext_vector_type(2)));

// vertical-pair value: VP(uy,ux) = half2{ P(uy,ux), P(uy+1,ux) },
// P(py,px) = img[py-1][px-1], zero outside (verified R10/R12/R13 builder).
__device__ __forceinline__ uint vp_pack(const float* im, int uy, int ux) {
    int x = ux - 1;
    if ((unsigned)x >= 256u) return 0u;
    float v0 = ((unsigned)(uy - 1) < 256u) ? im[((uy - 1) << 8) + x] : 0.0f;
    float v1 = ((unsigned)uy       < 256u) ? im[(uy << 8) + x]       : 0.0f;
    __half2 h2 = __floats2half2_rn(v0, v1);
    return *reinterpret_cast<uint*>(&h2);
}

// Gq[b*TN + uy*TW + ux] = { VP(uy,ux), VP(uy,ux+1) } : one 8B load fetches
// the whole bilinear footprint for floor coords (uy,ux).  (verified R13)
__global__ void quad_build(const float* __restrict__ src, uint2* __restrict__ dst) {
    int idx = blockIdx.x * blockDim.x + threadIdx.x;   // over 2*TN
    if (idx >= 2 * TN) return;
    int b  = idx / TN;
    int e  = idx - b * TN;
    int uy = e / TW;
    int ux = e - uy * TW;
    const float* im = src + (b << 16);
    uint2 q;
    q.x = vp_pack(im, uy, ux);
    q.y = vp_pack(im, uy, ux + 1);
    dst[idx] = q;
}

// Footprint-compacted mapping: one wave = 8 adjacent detectors x 8 sample
// slots. lane = slot*8 + det; each lane marches s = slo+slot, +8 through its
// ray's guard-free interval; shfl_xor-reduce the 8 slots; lanes 0..7 store.
__global__ __launch_bounds__(TPB) void fanproj_kernel(const uint2* __restrict__ Gq,
                                                      float* __restrict__ out) {
    int tid   = threadIdx.x;
    int lane  = tid & 63;
    int wv    = tid >> 6;
    int wray0 = (blockIdx.x << 5) + (wv << 3);         // 32 rays/block, 8/wave
    int slot  = lane >> 3;                             // 0..7 sample phase
    int ray   = wray0 + (lane & 7);                    // b*P*D + p*D + d

    int d  = ray % NDET;
    int pb = ray / NDET;
    int p  = pb & (NPROJ - 1);
    int b  = pb >> 8;

    const float dt = 1.4142135623730951f;              // diag / NS = sqrt(2)
    const float t0 = 219.68777079743137f;              // SID - diag/2 + 0.5*dt

    float theta = (float)p * (6.283185307179586f / (float)NPROJ);
    float st, ct;
    __sincosf(theta, &st, &ct);

    float srcx = -400.0f * ct;
    float srcy = -400.0f * st;
    float off  = ((float)d - 191.5f) * 1.2f;
    float rx   = fmaf(800.0f, ct, -off * st);
    float ry   = fmaf(800.0f, st,  off * ct);
    float n2   = rx * rx + ry * ry;
    float rn   = rsqrtf(n2);
    rn = rn * (1.5f - 0.5f * n2 * rn * rn);            // one Newton step
    rx *= rn;
    ry *= rn;

    // texture coords: X(s)=bxu+s*sx, Y(s)=byu+s*sy, footprint valid in [0,257)
    float bxu = fmaf(t0, rx, srcx) + 128.5f;
    float byu = fmaf(t0, ry, srcy) + 128.5f;
    float sx  = dt * rx;
    float sy  = dt * ry;

    // guard-free interval, EPS-shrunk (verified R8-R13)
    const float EPS = 2e-3f;
    float sxs = (fabsf(sx) < 1e-9f) ? copysignf(1e-9f, sx) : sx;
    float sys = (fabsf(sy) < 1e-9f) ? copysignf(1e-9f, sy) : sy;
    float isx = 1.0f / sxs;
    float isy = 1.0f / sys;
    float ax0 = (0.0f - bxu) * isx, ax1 = (257.0f - bxu) * isx;
    float ay0 = (0.0f - byu) * isy, ay1 = (257.0f - byu) * isy;
    float lof = fmaxf(fminf(ax0, ax1), fminf(ay0, ay1)) + EPS;
    float hif = fminf(fmaxf(ax0, ax1), fmaxf(ay0, ay1)) - EPS;
    lof = fminf(fmaxf(lof, -1.0f), 300.0f);
    hif = fminf(fmaxf(hif, -1.0f), 300.0f);
    int slo = max(0,      (int)ceilf(lof));
    int shi = min(NS - 1, (int)floorf(hif));

    const uint2* Gb = Gq + (size_t)b * TN;

    float acc = 0.0f;
    float sf  = (float)(slo + slot);
    for (int s = slo + slot; s <= shi; s += 8) {
        float X = fmaf(sf, sx, bxu);
        float Y = fmaf(sf, sy, byu);
        sf += 8.0f;
        float xf = floorf(X);
        float yf = floorf(Y);
        float wx = X - xf;
        float wy = Y - yf;
        float aF = fmaf(yf, 258.0f, xf);
        aF = fminf(fmaxf(aF, 0.0f), 66563.0f);         // drift safety clamp
        int ai = (int)aF;
        uint2 q = Gb[ai];                              // one 8B gather/sample
        hvec2 hw = __builtin_bit_cast(hvec2,
                       __builtin_amdgcn_cvt_pkrtz(1.0f - wy, wy));
        float c0 = __builtin_amdgcn_fdot2(__builtin_bit_cast(hvec2, q.x),
                                          hw, 0.0f, false);
        float c1 = __builtin_amdgcn_fdot2(__builtin_bit_cast(hvec2, q.y),
                                          hw, 0.0f, false);
        acc = fmaf(wx, c1 - c0, acc + c0);
    }

    // sum the 8 slot-partials: lanes sharing (lane&7) differ in bits 3..5
    acc += __shfl_xor(acc, 8,  64);
    acc += __shfl_xor(acc, 16, 64);
    acc += __shfl_xor(acc, 32, 64);
    if (slot == 0) out[ray] = acc * dt;                // 8 rays per wave, once
}

extern "C" void kernel_launch(void* const* d_in, const int* in_sizes, int n_in,
                              void* d_out, int out_size, void* d_ws, size_t ws_size,
                              hipStream_t stream) {
    const float* x = (const float*)d_in[0];
    float* out     = (float*)d_out;
    uint2* Gq      = (uint2*)d_ws;                     // 2*TN*8 B = 1.07 MB

    int nent = 2 * TN;                                 // 133128
    quad_build<<<(nent + 255) / 256, 256, 0, stream>>>(x, Gq);

    // 6144 blocks x 256 threads: 32 rays/block x 6144 = 196608 rays exactly
    fanproj_kernel<<<6144, TPB, 0, stream>>>(Gq, out);
}

// Round 15
// 75.026 us; speedup vs baseline: 1.2400x; 1.0910x over previous
//
#include <hip/hip_runtime.h>
#include <hip/hip_fp16.h>

#define NPROJ  256
#define NDET   384
#define NS     256
#define TW     258                 // texture entries per row (uy,ux in [0,258))
#define TN     (TW * TW)           // 66564 entries (16 B each, both batches)
#define NRAY   (NPROJ * NDET)      // rays per batch
#define TPB    256

typedef _Float16 hvec2 __attribute__((ext_vector_type(2)));

// vertical-pair value: VP(uy,ux) = half2{ P(uy,ux), P(uy+1,ux) },
// P(py,px) = img[py-1][px-1], zero outside (verified R10-R14 builder).
__device__ __forceinline__ uint vp_pack(const float* im, int uy, int ux) {
    int x = ux - 1;
    if ((unsigned)x >= 256u) return 0u;
    float v0 = ((unsigned)(uy - 1) < 256u) ? im[((uy - 1) << 8) + x] : 0.0f;
    float v1 = ((unsigned)uy       < 256u) ? im[(uy << 8) + x]       : 0.0f;
    __half2 h2 = __floats2half2_rn(v0, v1);
    return *reinterpret_cast<uint*>(&h2);
}

// Batch-paired quad texture: T[uy*TW+ux] = uint4{
//   b0 VP(uy,ux), b0 VP(uy,ux+1), b1 VP(uy,ux), b1 VP(uy,ux+1) }.
// One aligned 16B load serves the bilinear footprint of BOTH batch images.
__global__ void quad_build(const float* __restrict__ src, uint4* __restrict__ dst) {
    int e = blockIdx.x * blockDim.x + threadIdx.x;     // over TN
    if (e >= TN) return;
    int uy = e / TW;
    int ux = e - uy * TW;
    const float* im0 = src;
    const float* im1 = src + (1 << 16);
    uint4 q;
    q.x = vp_pack(im0, uy, ux);
    q.y = vp_pack(im0, uy, ux + 1);
    q.z = vp_pack(im1, uy, ux);
    q.w = vp_pack(im1, uy, ux + 1);
    dst[e] = q;
}

// Footprint-compacted + batch-paired: one wave = 8 adjacent detectors x 8
// sample slots; each lane's 16B gather covers one sample of BOTH batch rays.
// shfl_xor-reduce the 8 slots; lanes 0..7 store 8 ray-pairs (16 outputs).
__global__ __launch_bounds__(TPB) void fanproj_kernel(const uint4* __restrict__ T,
                                                      float* __restrict__ out) {
    int tid   = threadIdx.x;
    int lane  = tid & 63;
    int wv    = tid >> 6;
    int wrp0  = (blockIdx.x << 5) + (wv << 3);         // 32 ray-pairs/block
    int slot  = lane >> 3;                             // 0..7 sample phase
    int rp    = wrp0 + (lane & 7);                     // p*D + d  (pair id)

    int d = rp % NDET;
    int p = rp / NDET;                                 // in [0, NPROJ)

    const float dt = 1.4142135623730951f;              // diag / NS = sqrt(2)
    const float t0 = 219.68777079743137f;              // SID - diag/2 + 0.5*dt

    float theta = (float)p * (6.283185307179586f / (float)NPROJ);
    float st, ct;
    __sincosf(theta, &st, &ct);

    float srcx = -400.0f * ct;
    float srcy = -400.0f * st;
    float off  = ((float)d - 191.5f) * 1.2f;
    float rx   = fmaf(800.0f, ct, -off * st);
    float ry   = fmaf(800.0f, st,  off * ct);
    float n2   = rx * rx + ry * ry;
    float rn   = rsqrtf(n2);
    rn = rn * (1.5f - 0.5f * n2 * rn * rn);            // one Newton step
    rx *= rn;
    ry *= rn;

    // texture coords: X(s)=bxu+s*sx, Y(s)=byu+s*sy, footprint valid in [0,257)
    float bxu = fmaf(t0, rx, srcx) + 128.5f;
    float byu = fmaf(t0, ry, srcy) + 128.5f;
    float sx  = dt * rx;
    float sy  = dt * ry;

    // guard-free interval, EPS-shrunk (verified R8-R14); same for both batches
    const float EPS = 2e-3f;
    float sxs = (fabsf(sx) < 1e-9f) ? copysignf(1e-9f, sx) : sx;
    float sys = (fabsf(sy) < 1e-9f) ? copysignf(1e-9f, sy) : sy;
    float isx = 1.0f / sxs;
    float isy = 1.0f / sys;
    float ax0 = (0.0f - bxu) * isx, ax1 = (257.0f - bxu) * isx;
    float ay0 = (0.0f - byu) * isy, ay1 = (257.0f - byu) * isy;
    float lof = fmaxf(fminf(ax0, ax1), fminf(ay0, ay1)) + EPS;
    float hif = fminf(fmaxf(ax0, ax1), fmaxf(ay0, ay1)) - EPS;
    lof = fminf(fmaxf(lof, -1.0f), 300.0f);
    hif = fminf(fmaxf(hif, -1.0f), 300.0f);
    int slo = max(0,      (int)ceilf(lof));
    int shi = min(NS - 1, (int)floorf(hif));

    float acc0 = 0.0f, acc1 = 0.0f;
    float sf  = (float)(slo + slot);
    for (int s = slo + slot; s <= shi; s += 8) {
        float X = fmaf(sf, sx, bxu);
        float Y = fmaf(sf, sy, byu);
        sf += 8.0f;
        float xf = floorf(X);
        float yf = floorf(Y);
        float wx = X - xf;
        float wy = Y - yf;
        float aF = fmaf(yf, 258.0f, xf);
        aF = fminf(fmaxf(aF, 0.0f), 66563.0f);         // drift safety clamp
        int ai = (int)aF;
        uint4 q = T[ai];                               // one 16B gather: 2 batches
        hvec2 hw = __builtin_bit_cast(hvec2,
                       __builtin_amdgcn_cvt_pkrtz(1.0f - wy, wy));
        float c0 = __builtin_amdgcn_fdot2(__builtin_bit_cast(hvec2, q.x),
                                          hw, 0.0f, false);
        float c1 = __builtin_amdgcn_fdot2(__builtin_bit_cast(hvec2, q.y),
                                          hw, 0.0f, false);
        acc0 = fmaf(wx, c1 - c0, acc0 + c0);
        float c2 = __builtin_amdgcn_fdot2(__builtin_bit_cast(hvec2, q.z),
                                          hw, 0.0f, false);
        float c3 = __builtin_amdgcn_fdot2(__builtin_bit_cast(hvec2, q.w),
                                          hw, 0.0f, false);
        acc1 = fmaf(wx, c3 - c2, acc1 + c2);
    }

    // sum the 8 slot-partials (lanes sharing lane&7 differ in bits 3..5)
    acc0 += __shfl_xor(acc0, 8,  64);
    acc0 += __shfl_xor(acc0, 16, 64);
    acc0 += __shfl_xor(acc0, 32, 64);
    acc1 += __shfl_xor(acc1, 8,  64);
    acc1 += __shfl_xor(acc1, 16, 64);
    acc1 += __shfl_xor(acc1, 32, 64);
    if (slot == 0) {
        out[rp]        = acc0 * dt;                    // batch 0
        out[rp + NRAY] = acc1 * dt;                    // batch 1
    }
}

extern "C" void kernel_launch(void* const* d_in, const int* in_sizes, int n_in,
                              void* d_out, int out_size, void* d_ws, size_t ws_size,
                              hipStream_t stream) {
    const float* x = (const float*)d_in[0];
    float* out     = (float*)d_out;
    uint4* T       = (uint4*)d_ws;                     // TN*16 B = 1.07 MB

    quad_build<<<(TN + 255) / 256, 256, 0, stream>>>(x, T);

    // 3072 blocks x 256 threads: 32 ray-pairs/block x 3072 = 98304 pairs
    fanproj_kernel<<<3072, TPB, 0, stream>>>(T, out);
}

// Round 16
// 71.613 us; speedup vs baseline: 1.2991x; 1.0477x over previous
//
#include <hip/hip_runtime.h>
#include <hip/hip_fp16.h>

#define NPROJ  256
#define NDET   384
#define NS     256
#define TW     258                 // texture entries per row (uy,ux in [0,258))
#define TN     (TW * TW)           // 66564 entries (16 B each, both batches)
#define NRAY   (NPROJ * NDET)      // rays per batch
#define TPB    256

typedef _Float16 hvec2 __attribute__((ext_vector_type(2)));

// vertical-pair value: VP(uy,ux) = half2{ P(uy,ux), P(uy+1,ux) },
// P(py,px) = img[py-1][px-1], zero outside (verified R10-R15 builder).
__device__ __forceinline__ uint vp_pack(const float* im, int uy, int ux) {
    int x = ux - 1;
    if ((unsigned)x >= 256u) return 0u;
    float v0 = ((unsigned)(uy - 1) < 256u) ? im[((uy - 1) << 8) + x] : 0.0f;
    float v1 = ((unsigned)uy       < 256u) ? im[(uy << 8) + x]       : 0.0f;
    __half2 h2 = __floats2half2_rn(v0, v1);
    return *reinterpret_cast<uint*>(&h2);
}

// Batch-paired quad texture (verified R15): T[uy*TW+ux] = uint4{
//   b0 VP(uy,ux), b0 VP(uy,ux+1), b1 VP(uy,ux), b1 VP(uy,ux+1) }.
__global__ void quad_build(const float* __restrict__ src, uint4* __restrict__ dst) {
    int e = blockIdx.x * blockDim.x + threadIdx.x;     // over TN
    if (e >= TN) return;
    int uy = e / TW;
    int ux = e - uy * TW;
    const float* im0 = src;
    const float* im1 = src + (1 << 16);
    uint4 q;
    q.x = vp_pack(im0, uy, ux);
    q.y = vp_pack(im0, uy, ux + 1);
    q.z = vp_pack(im1, uy, ux);
    q.w = vp_pack(im1, uy, ux + 1);
    dst[e] = q;
}

// Footprint-compacted (8 det x 8 slots, verified R14) + batch-paired (R15)
// + 2-deep MLP: each lane handles samples s and s+8 per iteration, two 16B
// gathers in flight. Sample B tail-masked by weight-zeroing (R13 technique).
__global__ __launch_bounds__(TPB) void fanproj_kernel(const uint4* __restrict__ T,
                                                      float* __restrict__ out) {
    int tid   = threadIdx.x;
    int lane  = tid & 63;
    int wv    = tid >> 6;
    int wrp0  = (blockIdx.x << 5) + (wv << 3);         // 32 ray-pairs/block
    int slot  = lane >> 3;                             // 0..7 sample phase
    int rp    = wrp0 + (lane & 7);                     // p*D + d  (pair id)

    int d = rp % NDET;
    int p = rp / NDET;                                 // in [0, NPROJ)

    const float dt = 1.4142135623730951f;              // diag / NS = sqrt(2)
    const float t0 = 219.68777079743137f;              // SID - diag/2 + 0.5*dt

    float theta = (float)p * (6.283185307179586f / (float)NPROJ);
    float st, ct;
    __sincosf(theta, &st, &ct);

    float srcx = -400.0f * ct;
    float srcy = -400.0f * st;
    float off  = ((float)d - 191.5f) * 1.2f;
    float rx   = fmaf(800.0f, ct, -off * st);
    float ry   = fmaf(800.0f, st,  off * ct);
    float n2   = rx * rx + ry * ry;
    float rn   = rsqrtf(n2);
    rn = rn * (1.5f - 0.5f * n2 * rn * rn);            // one Newton step
    rx *= rn;
    ry *= rn;

    // texture coords: X(s)=bxu+s*sx, Y(s)=byu+s*sy, footprint valid in [0,257)
    float bxu = fmaf(t0, rx, srcx) + 128.5f;
    float byu = fmaf(t0, ry, srcy) + 128.5f;
    float sx  = dt * rx;
    float sy  = dt * ry;

    // guard-free interval, EPS-shrunk (verified R8-R15); same for both batches
    const float EPS = 2e-3f;
    float sxs = (fabsf(sx) < 1e-9f) ? copysignf(1e-9f, sx) : sx;
    float sys = (fabsf(sy) < 1e-9f) ? copysignf(1e-9f, sy) : sy;
    float isx = 1.0f / sxs;
    float isy = 1.0f / sys;
    float ax0 = (0.0f - bxu) * isx, ax1 = (257.0f - bxu) * isx;
    float ay0 = (0.0f - byu) * isy, ay1 = (257.0f - byu) * isy;
    float lof = fmaxf(fminf(ax0, ax1), fminf(ay0, ay1)) + EPS;
    float hif = fminf(fmaxf(ax0, ax1), fmaxf(ay0, ay1)) - EPS;
    lof = fminf(fmaxf(lof, -1.0f), 300.0f);
    hif = fminf(fmaxf(hif, -1.0f), 300.0f);
    int slo = max(0,      (int)ceilf(lof));
    int shi = min(NS - 1, (int)floorf(hif));

    int s0  = slo + slot;
    int rem = shi - s0;                                // >=0: sample A valid
    float sf = (float)s0;
    float accA0 = 0.0f, accA1 = 0.0f;                  // chain A (s)
    float accB0 = 0.0f, accB1 = 0.0f;                  // chain B (s+8)

    while (rem >= 0) {
        float XA = fmaf(sf, sx, bxu);
        float YA = fmaf(sf, sy, byu);
        float sfB = sf + 8.0f;
        float XB = fmaf(sfB, sx, bxu);
        float YB = fmaf(sfB, sy, byu);
        sf += 16.0f;

        float xfA = floorf(XA), yfA = floorf(YA);
        float wxA = XA - xfA,  wyA = YA - yfA;
        float aFA = fmaf(yfA, 258.0f, xfA);
        aFA = fminf(fmaxf(aFA, 0.0f), 66563.0f);       // drift safety clamp
        int aiA = (int)aFA;

        float xfB = floorf(XB), yfB = floorf(YB);
        float wxB = XB - xfB,  wyB = YB - yfB;
        float aFB = fmaf(yfB, 258.0f, xfB);
        aFB = fminf(fmaxf(aFB, 0.0f), 66563.0f);       // clamp covers tail OOB
        int aiB = (int)aFB;

        uint4 qA = T[aiA];                             // 2 x 16B gathers in flight
        uint4 qB = T[aiB];

        // sample A: always valid inside the loop (rem >= 0)
        hvec2 hwA = __builtin_bit_cast(hvec2,
                        __builtin_amdgcn_cvt_pkrtz(1.0f - wyA, wyA));
        float a0 = __builtin_amdgcn_fdot2(__builtin_bit_cast(hvec2, qA.x),
                                          hwA, 0.0f, false);
        float a1 = __builtin_amdgcn_fdot2(__builtin_bit_cast(hvec2, qA.y),
                                          hwA, 0.0f, false);
        accA0 = fmaf(wxA, a1 - a0, accA0 + a0);
        float a2 = __builtin_amdgcn_fdot2(__builtin_bit_cast(hvec2, qA.z),
                                          hwA, 0.0f, false);
        float a3 = __builtin_amdgcn_fdot2(__builtin_bit_cast(hvec2, qA.w),
                                          hwA, 0.0f, false);
        accA1 = fmaf(wxA, a3 - a2, accA1 + a2);

        // sample B: tail-masked by zeroed weights (contributes exactly 0)
        uint hwBb = __builtin_bit_cast(uint,
                        __builtin_amdgcn_cvt_pkrtz(1.0f - wyB, wyB));
        hwBb = (rem >= 8) ? hwBb : 0u;
        hvec2 hwB = __builtin_bit_cast(hvec2, hwBb);
        float b0 = __builtin_amdgcn_fdot2(__builtin_bit_cast(hvec2, qB.x),
                                          hwB, 0.0f, false);
        float b1 = __builtin_amdgcn_fdot2(__builtin_bit_cast(hvec2, qB.y),
                                          hwB, 0.0f, false);
        accB0 = fmaf(wxB, b1 - b0, accB0 + b0);
        float b2 = __builtin_amdgcn_fdot2(__builtin_bit_cast(hvec2, qB.z),
                                          hwB, 0.0f, false);
        float b3 = __builtin_amdgcn_fdot2(__builtin_bit_cast(hvec2, qB.w),
                                          hwB, 0.0f, false);
        accB1 = fmaf(wxB, b3 - b2, accB1 + b2);

        rem -= 16;
    }

    float acc0 = accA0 + accB0;
    float acc1 = accA1 + accB1;

    // sum the 8 slot-partials (lanes sharing lane&7 differ in bits 3..5)
    acc0 += __shfl_xor(acc0, 8,  64);
    acc0 += __shfl_xor(acc0, 16, 64);
    acc0 += __shfl_xor(acc0, 32, 64);
    acc1 += __shfl_xor(acc1, 8,  64);
    acc1 += __shfl_xor(acc1, 16, 64);
    acc1 += __shfl_xor(acc1, 32, 64);
    if (slot == 0) {
        out[rp]        = acc0 * dt;                    // batch 0
        out[rp + NRAY] = acc1 * dt;                    // batch 1
    }
}

extern "C" void kernel_launch(void* const* d_in, const int* in_sizes, int n_in,
                              void* d_out, int out_size, void* d_ws, size_t ws_size,
                              hipStream_t stream) {
    const float* x = (const float*)d_in[0];
    float* out     = (float*)d_out;
    uint4* T       = (uint4*)d_ws;                     // TN*16 B = 1.07 MB

    quad_build<<<(TN + 255) / 256, 256, 0, stream>>>(x, T);

    // 3072 blocks x 256 threads: 32 ray-pairs/block x 3072 = 98304 pairs
    fanproj_kernel<<<3072, TPB, 0, stream>>>(T, out);
}